// Round 1
// 415.269 us; speedup vs baseline: 1.0202x; 1.0202x over previous
//
#include <hip/hip_runtime.h>
#include <hip/hip_bf16.h>

// Flash attention fwd, 1 head, B=64, S=1024, D=256.
// Inputs/outputs fp32 (per reference); compute in bf16 MFMA, fp32 accum.
// A bf16-I/O variant is kept as insurance; on-device dtype detection picks
// one, the other exits immediately (graph-capture-safe, same work each call).
// Block = 256 thr (4 waves); each block: one (batch, 64-row Q tile).
//
// R1: PV no longer gathers V with 256 scalar ds_read_u16/wave (4-way bank
// conflicted -> the measured 4.2e7 SQ_LDS_BANK_CONFLICT). A second LDS copy
// `vs` stores the tile as 16B granules (8 kv-consecutive elems of one d) with
// bank-slot rotation addr(d,kc) = (d>>3)*1024 + (d&7)*128 + ((kc+d)&7)*16:
//  - PV reads:    b128, lanes cover 8 slots x 8 lanes -> conflict-free
//  - vt writes:   b128, thread d=tid, slot (g+d)&7    -> conflict-free
//  - vt src reads: ks column reads, 2B/lane consecutive -> conflict-free
// Built once per tile from ks, amortized over all 4 waves.
// Also: QK scale folded into softmax exponent constant (exp2 base change).

#define NB   64
#define NQ   1024
#define NKV  1024
#define DM   256
#define BQ   64     // q rows per block
#define BK   64     // kv rows per tile
#define KPAD 264    // ks row stride (elems): QK^T b128 reads land 8 slots x 8 lanes
#define PPAD 72     // p_lds row stride (elems): 144B, 16B-aligned
#define LOG2E   1.4426950408889634f
#define SCL     (0.0625f * LOG2E)   // fold scale=256^-0.5 into exp2 arg
#define NEG_BIG (-1e30f)   // finite "-inf"

typedef __attribute__((ext_vector_type(8))) short  bf16x8;   // 8 bf16 = 4 VGPRs
typedef __attribute__((ext_vector_type(4))) float  floatx4;

__device__ __forceinline__ ushort f2bf(float f) {
  __hip_bfloat16 h = __float2bfloat16(f);
  return *(ushort*)&h;
}

// flag=1: data is bf16; flag=0: data is fp32.
__global__ void detect_dtype(const unsigned int* __restrict__ q,
                             int* __restrict__ flag) {
  __shared__ int cnt;
  if (threadIdx.x == 0) cnt = 0;
  __syncthreads();
  unsigned int w = q[(size_t)threadIdx.x * 32003u];
  unsigned int e = (w >> 7) & 0xFFu;
  int good = (e >= 96u && e < 160u) ? 1 : 0;
  atomicAdd(&cnt, good);
  __syncthreads();
  if (threadIdx.x == 0) flag[0] = (cnt > 192) ? 1 : 0;
}

template <bool IS_BF16>
__global__ __launch_bounds__(256, 2) void attn_fwd(
    const void* __restrict__ qv, const void* __restrict__ kvv,
    void* __restrict__ outv, const int* __restrict__ flag)
{
  if (flag[0] != (IS_BF16 ? 1 : 0)) return;   // block-uniform: barrier-safe

  __shared__ ushort ks[BK * KPAD];           // kv tile, row-major padded (~33KB)
  __shared__ ushort vs[BK * DM];             // granule-transposed V copy (32KB)
  __shared__ ushort ps[4 * 16 * PPAD];       // per-wave P staging (~9KB)

  const int tid   = threadIdx.x;
  const int wave  = tid >> 6;
  const int lane  = tid & 63;
  const int quad  = lane >> 4;
  const int l16   = lane & 15;
  const int batch = blockIdx.y;
  const int q0    = blockIdx.x * BQ + wave * 16;

  // Q fragments, A-layout: a[j] = Q[m=l16][k = kb*32 + quad*8 + j]
  bf16x8 qf[8];
  if constexpr (IS_BF16) {
    const ushort* qp = (const ushort*)qv + ((size_t)(batch * NQ + q0 + l16)) * DM + quad * 8;
#pragma unroll
    for (int kb = 0; kb < 8; ++kb)
      qf[kb] = *(const bf16x8*)(qp + kb * 32);
  } else {
    const float* qp = (const float*)qv + ((size_t)(batch * NQ + q0 + l16)) * DM + quad * 8;
#pragma unroll
    for (int kb = 0; kb < 8; ++kb) {
      float4 f0 = *(const float4*)(qp + kb * 32);
      float4 f1 = *(const float4*)(qp + kb * 32 + 4);
      bf16x8 o; ushort* op = (ushort*)&o;
      op[0]=f2bf(f0.x); op[1]=f2bf(f0.y); op[2]=f2bf(f0.z); op[3]=f2bf(f0.w);
      op[4]=f2bf(f1.x); op[5]=f2bf(f1.y); op[6]=f2bf(f1.z); op[7]=f2bf(f1.w);
      qf[kb] = o;
    }
  }

  floatx4 acc[16];                // O acc, C-layout: acc[nt][r] = O[quad*4+r][nt*16+l16]
#pragma unroll
  for (int i = 0; i < 16; ++i) acc[i] = (floatx4){0.f, 0.f, 0.f, 0.f};
  float m_i[4] = {NEG_BIG, NEG_BIG, NEG_BIG, NEG_BIG};   // UNSCALED running max
  float l_i[4] = {0.f, 0.f, 0.f, 0.f};

  // PV read bases (loop-invariant): d = nt*16 + l16
  const int dlo = l16 & 7;
  const ushort* vb0 = vs + ((l16 >> 3) << 9) + (dlo << 6);
  const int sl0 = ((quad + dlo) & 7) << 3;        // kf=0 : kc = quad
  const int sl1 = ((quad + 4 + dlo) & 7) << 3;    // kf=1 : kc = quad+4

  for (int kt = 0; kt < NKV / BK; ++kt) {
    __syncthreads();  // protect ks/vs from previous iteration's readers
    // ---- stage kv tile 64x256 into LDS as bf16 (row-major) ----
    if constexpr (IS_BF16) {
      const ushort* src = (const ushort*)kvv + ((size_t)batch * NKV + kt * BK) * DM;
#pragma unroll
      for (int i = 0; i < 8; ++i) {
        int v = tid + i * 256;      // 2048 vec8 chunks
        int r = v >> 5;             // 32 vec8 per row
        int c = (v & 31) << 3;
        *(bf16x8*)&ks[r * KPAD + c] = *(const bf16x8*)&src[r * DM + c];
      }
    } else {
      const float* src = (const float*)kvv + ((size_t)batch * NKV + kt * BK) * DM;
#pragma unroll
      for (int i = 0; i < 8; ++i) {
        int v = tid + i * 256;
        int r = v >> 5;
        int c = (v & 31) << 3;
        const float* sp = src + r * DM + c;
        float4 f0 = *(const float4*)(sp);
        float4 f1 = *(const float4*)(sp + 4);
        bf16x8 o; ushort* op = (ushort*)&o;
        op[0]=f2bf(f0.x); op[1]=f2bf(f0.y); op[2]=f2bf(f0.z); op[3]=f2bf(f0.w);
        op[4]=f2bf(f1.x); op[5]=f2bf(f1.y); op[6]=f2bf(f1.z); op[7]=f2bf(f1.w);
        *(bf16x8*)&ks[r * KPAD + c] = o;
      }
    }
    __syncthreads();

    // ---- S = Q @ K^T (unscaled) : 16x64 per wave ----
    // b[j] = K[n=nt*16+l16][k=kb*32+quad*8+j]  (row-major read == A*B^T trick)
    floatx4 s[4];
#pragma unroll
    for (int nt = 0; nt < 4; ++nt) {
      floatx4 a = (floatx4){0.f, 0.f, 0.f, 0.f};
#pragma unroll
      for (int kb = 0; kb < 8; ++kb) {
        bf16x8 bfr = *(const bf16x8*)&ks[(nt * 16 + l16) * KPAD + kb * 32 + quad * 8];
        a = __builtin_amdgcn_mfma_f32_16x16x32_bf16(qf[kb], bfr, a, 0, 0, 0);
      }
      s[nt] = a;
    }

    // ---- build granule-transposed V copy: thread owns column d = tid ----
    // granule g (kv = g*8..g*8+7) -> vs[(d>>3)*512 + (d&7)*64 + ((g+d)&7)*8]
    {
      const ushort* kcol = ks + tid;
      ushort* col = vs + ((tid >> 3) << 9) + ((tid & 7) << 6);
      const int rot = tid & 7;
#pragma unroll
      for (int g = 0; g < 8; ++g) {
        bf16x8 o; ushort* op = (ushort*)&o;
#pragma unroll
        for (int i = 0; i < 8; ++i)
          op[i] = kcol[(g * 8 + i) * KPAD];
        *(bf16x8*)&col[((g + rot) & 7) << 3] = o;
      }
    }

    // ---- online softmax (row quad*4+r; cols in the quad's 16 lanes x 4 nt) ----
    // scale folded into exponent: p = exp2((s - m) * 0.0625 * log2e)
    float pv[4][4];  // [nt][r]
#pragma unroll
    for (int r = 0; r < 4; ++r) {
      float mx = fmaxf(fmaxf(s[0][r], s[1][r]), fmaxf(s[2][r], s[3][r]));
      mx = fmaxf(mx, __shfl_xor(mx, 1));
      mx = fmaxf(mx, __shfl_xor(mx, 2));
      mx = fmaxf(mx, __shfl_xor(mx, 4));
      mx = fmaxf(mx, __shfl_xor(mx, 8));
      float mnew  = fmaxf(m_i[r], mx);                        // finite always
      float alpha = exp2f(fmaxf((m_i[r] - mnew) * SCL, -126.f));
      float rs = 0.f;
#pragma unroll
      for (int nt = 0; nt < 4; ++nt) {
        float p = exp2f((s[nt][r] - mnew) * SCL);
        pv[nt][r] = p;
        rs += p;
      }
      rs += __shfl_xor(rs, 1);
      rs += __shfl_xor(rs, 2);
      rs += __shfl_xor(rs, 4);
      rs += __shfl_xor(rs, 8);
      l_i[r] = l_i[r] * alpha + rs;
      m_i[r] = mnew;
#pragma unroll
      for (int nt = 0; nt < 16; ++nt) acc[nt][r] *= alpha;
    }

    // ---- P: C-layout regs -> LDS -> A-layout frags ----
    ushort* pw = ps + wave * 16 * PPAD;
#pragma unroll
    for (int nt = 0; nt < 4; ++nt)
#pragma unroll
      for (int r = 0; r < 4; ++r)
        pw[(quad * 4 + r) * PPAD + nt * 16 + l16] = f2bf(pv[nt][r]);
    __syncthreads();   // ps ready AND vs fully built

    bf16x8 pf[2];
#pragma unroll
    for (int kf = 0; kf < 2; ++kf)
      pf[kf] = *(const bf16x8*)&pw[l16 * PPAD + kf * 32 + quad * 8];

    // ---- O += P @ V : b[j] = V[k=kf*32+quad*8+j][n=nt*16+l16] via vs b128 ----
#pragma unroll
    for (int nt = 0; nt < 16; ++nt) {
      const ushort* vb = vb0 + (nt << 10);
      bf16x8 v0 = *(const bf16x8*)(vb + sl0);
      acc[nt] = __builtin_amdgcn_mfma_f32_16x16x32_bf16(pf[0], v0, acc[nt], 0, 0, 0);
      bf16x8 v1 = *(const bf16x8*)(vb + sl1);
      acc[nt] = __builtin_amdgcn_mfma_f32_16x16x32_bf16(pf[1], v1, acc[nt], 0, 0, 0);
    }
  }

  // ---- epilogue: O / l, store in the REFERENCE dtype ----
#pragma unroll
  for (int r = 0; r < 4; ++r) l_i[r] = 1.f / l_i[r];
  if constexpr (IS_BF16) {
    ushort* ob = (ushort*)outv + ((size_t)(batch * NQ + q0 + quad * 4)) * DM + l16;
#pragma unroll
    for (int nt = 0; nt < 16; ++nt)
#pragma unroll
      for (int r = 0; r < 4; ++r)
        ob[(size_t)r * DM + nt * 16] = f2bf(acc[nt][r] * l_i[r]);
  } else {
    float* ob = (float*)outv + ((size_t)(batch * NQ + q0 + quad * 4)) * DM + l16;
#pragma unroll
    for (int nt = 0; nt < 16; ++nt)
#pragma unroll
      for (int r = 0; r < 4; ++r)
        ob[(size_t)r * DM + nt * 16] = acc[nt][r] * l_i[r];
  }
}

extern "C" void kernel_launch(void* const* d_in, const int* in_sizes, int n_in,
                              void* d_out, int out_size, void* d_ws, size_t ws_size,
                              hipStream_t stream) {
  const void* q  = d_in[0];
  const void* kv = d_in[1];
  int* flag      = (int*)d_ws;

  detect_dtype<<<dim3(1), dim3(256), 0, stream>>>((const unsigned int*)q, flag);

  dim3 grid(NQ / BQ, NB);
  attn_fwd<true ><<<grid, dim3(256), 0, stream>>>(q, kv, d_out, flag);
  attn_fwd<false><<<grid, dim3(256), 0, stream>>>(q, kv, d_out, flag);
}